// Round 13
// baseline (16.563 us; speedup 1.0000x reference)
//
#include <hip/hip_runtime.h>
#include <math.h>

// Problem constants (from reference setup_inputs): B=32, N=256, D=32.
#define BB 32
#define NN 256
#define DD 32
#define NBLK (BB * 3 * 4 * 4)    // (b, type, i-quarter, j-quarter) = 1536
#define NPART NBLK
// ws float offsets
#define NORM_OFF  4096           // [side2][b32][row256] = 16384 floats
#define FRAG_HI_OFF 32768        // [plane64][tile16][lane64] x 16B = 262144 floats
#define FRAG_LO_OFF (32768 + 262144)

typedef short  bf16x8 __attribute__((ext_vector_type(8)));
typedef float  f32x4  __attribute__((ext_vector_type(4)));

__device__ __forceinline__ unsigned cvt_pk_bf16(float a, float b) {
    unsigned r;
    asm("v_cvt_pk_bf16_f32 %0, %1, %2" : "=v"(r) : "v"(a), "v"(b));
    return r;   // bits[15:0] = bf16(a), [31:16] = bf16(b)  (RNE)
}

// Prep: fp32 rows -> bf16 hi/lo fragments in MFMA lane order + row norms.
// Fragment layout (verified by R12's absmax=0): lane l of tile t holds
// row t*16+(l&15), k = (l>>4)*8 .. +7. plane p = side*32 + b.
// Block = (b, side, quarter of 64 rows); thread = one row.
__global__ __launch_bounds__(64) void mmd_prep(
    const float* __restrict__ x, const float* __restrict__ y,
    float* __restrict__ ws) {
    const int blk  = blockIdx.x;          // 256 = b(32) * side(2) * q(4)
    const int b    = blk >> 3;
    const int side = (blk >> 2) & 1;
    const int q    = blk & 3;
    const int r    = q * 64 + threadIdx.x;    // row 0..255
    const float* src = side ? y : x;
    const float4* rp = (const float4*)(src + ((size_t)b * NN + r) * DD);

    const int p = side * 32 + b;
    uint4* fh = (uint4*)(ws + FRAG_HI_OFF);
    uint4* fl = (uint4*)(ws + FRAG_LO_OFF);

    float c0 = 0.f, c1 = 0.f, c2 = 0.f, c3 = 0.f;
    #pragma unroll
    for (int g = 0; g < 4; ++g) {             // k-group of 8
        const float4 v0 = rp[2 * g], v1 = rp[2 * g + 1];
        c0 = fmaf(v0.x, v0.x, c0); c1 = fmaf(v0.y, v0.y, c1);
        c2 = fmaf(v0.z, v0.z, c2); c3 = fmaf(v0.w, v0.w, c3);
        c0 = fmaf(v1.x, v1.x, c0); c1 = fmaf(v1.y, v1.y, c1);
        c2 = fmaf(v1.z, v1.z, c2); c3 = fmaf(v1.w, v1.w, c3);

        const unsigned h01 = cvt_pk_bf16(v0.x, v0.y);
        const unsigned h23 = cvt_pk_bf16(v0.z, v0.w);
        const unsigned h45 = cvt_pk_bf16(v1.x, v1.y);
        const unsigned h67 = cvt_pk_bf16(v1.z, v1.w);
        // residuals: x - as_float(hi bits in high half)
        const float r0 = v0.x - __uint_as_float(h01 << 16);
        const float r1 = v0.y - __uint_as_float(h01 & 0xffff0000u);
        const float r2 = v0.z - __uint_as_float(h23 << 16);
        const float r3 = v0.w - __uint_as_float(h23 & 0xffff0000u);
        const float r4 = v1.x - __uint_as_float(h45 << 16);
        const float r5 = v1.y - __uint_as_float(h45 & 0xffff0000u);
        const float r6 = v1.z - __uint_as_float(h67 << 16);
        const float r7 = v1.w - __uint_as_float(h67 & 0xffff0000u);
        const unsigned l01 = cvt_pk_bf16(r0, r1);
        const unsigned l23 = cvt_pk_bf16(r2, r3);
        const unsigned l45 = cvt_pk_bf16(r4, r5);
        const unsigned l67 = cvt_pk_bf16(r6, r7);

        const int slot = (p * 16 + (r >> 4)) * 64 + g * 16 + (r & 15);
        fh[slot] = make_uint4(h01, h23, h45, h67);
        fl[slot] = make_uint4(l01, l23, l45, l67);
    }
    ws[NORM_OFF + p * NN + r] = (c0 + c1) + (c2 + c3);
}

// type 0: (x,x) +1 | type 1: (y,y) +1 | type 2: (x,y) -2
// Main: no LDS staging, no conversion — lanes load their MFMA fragments
// directly from the prepped planes (coalesced 16B), 12 MFMA + epilogue.
// Diagonal of xx/yy forced to sq=0 (exact clamp semantics, as in R12).
__global__ __launch_bounds__(256) void mmd_main(
    const float* __restrict__ w, float* ws) {
    const float*  norms = ws + NORM_OFF;
    const bf16x8* fh = (const bf16x8*)(ws + FRAG_HI_OFF);
    const bf16x8* fl = (const bf16x8*)(ws + FRAG_LO_OFF);
    float* partials = ws;                 // [0..NPART)

    const int blk = blockIdx.x;
    const int b   = blk / 48;
    int rem = blk - b * 48;
    const int type = rem >> 4;
    rem &= 15;
    const int iq = rem >> 2;              // i-quarter (64 rows)
    const int jq = rem & 3;               // j-quarter (64 cols)
    const int tid  = threadIdx.x;
    const int wv   = tid >> 6;            // wave = one j-tile of 16
    const int lane = tid & 63;

    const int pA = (type == 1 ? 32 : 0) + b;
    const int pB = (type == 0 ? 0 : 32) + b;

    const int bslot = (pB * 16 + jq * 4 + wv) * 64 + lane;
    const bf16x8 bh = fh[bslot];
    const bf16x8 bl = fl[bslot];
    const float  b2 = norms[pB * NN + jq * 64 + wv * 16 + (lane & 15)];
    const float  negw = -w[b] * (1.0f / (float)DD);
    const bool   sym = (type < 2) && (iq == jq);
    const int    rowbase = (lane >> 4) * 4;
    const int    colr = lane & 15;

    float acc = 0.f;
    #pragma unroll
    for (int it = 0; it < 4; ++it) {
        const int aslot = (pA * 16 + iq * 4 + it) * 64 + lane;
        const bf16x8 ah = fh[aslot];
        const bf16x8 al = fl[aslot];
        f32x4 c = {0.f, 0.f, 0.f, 0.f};
        c = __builtin_amdgcn_mfma_f32_16x16x32_bf16(al, bh, c, 0, 0, 0);
        c = __builtin_amdgcn_mfma_f32_16x16x32_bf16(ah, bl, c, 0, 0, 0);
        c = __builtin_amdgcn_mfma_f32_16x16x32_bf16(ah, bh, c, 0, 0, 0);
        const f32x4 a2q =
            *(const f32x4*)&norms[pA * NN + iq * 64 + it * 16 + rowbase];
        const bool diagt = sym && (it == wv);
        #pragma unroll
        for (int r = 0; r < 4; ++r) {
            float sq = fmaf(-2.0f, c[r], a2q[r] + b2);
            if (diagt && (rowbase + r == colr)) sq = 0.f;
            sq = fmaxf(sq, 1e-8f);   // folds norm clamp: sqrt(1e-8) = 1e-4
            acc += __expf(negw * __builtin_amdgcn_sqrtf(sq));
        }
    }

    // Deterministic block reduction: wave shuffle + fixed-order cross-wave.
    #pragma unroll
    for (int off = 32; off > 0; off >>= 1) acc += __shfl_down(acc, off, 64);
    __shared__ float red[4];
    if (lane == 0) red[wv] = acc;
    __syncthreads();
    if (tid == 0) {
        const float bsum = (red[0] + red[1]) + (red[2] + red[3]);
        const float weight = (type == 2) ? -2.0f : 1.0f;
        const float scale  = weight / ((float)NN * (float)NN * (float)BB);
        partials[blk] = bsum * scale;
    }
}

// Final deterministic reduction of NPART partials in double.
__global__ __launch_bounds__(256) void mmd_reduce(
    const float* __restrict__ partials, float* __restrict__ out) {
    double acc = 0.0;
    #pragma unroll
    for (int t = 0; t < NPART / 256; ++t)
        acc += (double)partials[threadIdx.x + t * 256];
    #pragma unroll
    for (int off = 32; off > 0; off >>= 1) acc += __shfl_down(acc, off, 64);
    __shared__ double red[4];
    if ((threadIdx.x & 63) == 0) red[threadIdx.x >> 6] = acc;
    __syncthreads();
    if (threadIdx.x == 0)
        out[0] = (float)((red[0] + red[1]) + (red[2] + red[3]));
}

extern "C" void kernel_launch(void* const* d_in, const int* in_sizes, int n_in,
                              void* d_out, int out_size, void* d_ws, size_t ws_size,
                              hipStream_t stream) {
    const float* x = (const float*)d_in[0];
    const float* y = (const float*)d_in[1];
    const float* w = (const float*)d_in[2];
    float* out = (float*)d_out;
    float* ws  = (float*)d_ws;

    mmd_prep<<<BB * 2 * 4, 64, 0, stream>>>(x, y, ws);
    mmd_main<<<NBLK, 256, 0, stream>>>(w, ws);
    mmd_reduce<<<1, 256, 0, stream>>>(ws, out);
}

// Round 14
// 12.592 us; speedup vs baseline: 1.3154x; 1.3154x over previous
//
#include <hip/hip_runtime.h>
#include <math.h>

// Problem constants (from reference setup_inputs): B=32, N=256, D=32.
#define BB 32
#define NN 256
#define DD 32
#define TPB 256
// Blocks per batch: xx upper-tri (10) + yy upper-tri (10) + xy full (16).
#define BPB 36
#define NBLK (BB * BPB)          // 1152
#define NPART NBLK

typedef short  bf16x8 __attribute__((ext_vector_type(8)));
typedef float  f32x4  __attribute__((ext_vector_type(4)));

__device__ __forceinline__ unsigned cvt_pk_bf16(float a, float b) {
    unsigned r;
    asm("v_cvt_pk_bf16_f32 %0, %1, %2" : "=v"(r) : "v"(a), "v"(b));
    return r;   // bits[15:0] = bf16(a), [31:16] = bf16(b)  (RNE; R13-verified)
}
__device__ __forceinline__ float fast_sqrt(float x) {
    float r;
    asm("v_sqrt_f32 %0, %1" : "=v"(r) : "v"(x));
    return r;
}
__device__ __forceinline__ float fast_exp2(float x) {
    float r;
    asm("v_exp_f32 %0, %1" : "=v"(r) : "v"(x));   // 2^x; input in [-0.36,0]
    return r;
}

// type 0: (x,x) | type 1: (y,y) | type 2: (x,y)
// Symmetric types compute only iq<=jq tiles; off-diagonal tiles weighted 2x
// (bitwise-exact: MFMA accumulation is A/B-symmetric, a2+b2 symmetric).
// Diagonal of xx/yy forced to sq=0 (exact clamp semantics, as in R12).
__global__ __launch_bounds__(TPB) void mmd_main(
    const float* __restrict__ x, const float* __restrict__ y,
    const float* __restrict__ w, float* __restrict__ partials) {
    const int blk = blockIdx.x;
    const int b   = blk / BPB;
    const int rem = blk - b * BPB;
    const int type = (rem >= 10) + (rem >= 20);
    int iq, jq;
    float weight;
    if (type == 2) {
        const int k = rem - 20;
        iq = k >> 2; jq = k & 3;
        weight = -2.0f;
    } else {
        const int k = rem - type * 10;
        iq = (k >= 4) + (k >= 7) + (k >= 9);
        jq = iq + k - ((9 * iq - iq * iq) >> 1);
        weight = (iq == jq) ? 1.0f : 2.0f;
    }
    const int tid  = threadIdx.x;
    const int wv   = tid >> 6;       // wave = one j-tile of 16
    const int lane = tid & 63;

    const float* Abase = (type == 1) ? y : x;
    const float* Bbase = (type == 0) ? x : y;
    const float* Aq = Abase + ((size_t)b * NN + iq * 64) * DD;  // 64 rows
    const float* Bq = Bbase + ((size_t)b * NN + jq * 64) * DD;  // 64 rows

    // LDS fragments [tile(4)][lane(64)]: lane l of tile t holds row
    // t*16+(l&15), k=(l>>4)*8..+7 (layout verified by R12 absmax=0).
    __shared__ bf16x8 Ah[4 * 64], Al[4 * 64], Bh[4 * 64], Bl[4 * 64];
    __shared__ float a2s[64], b2s[64];

    #pragma unroll
    for (int u = 0; u < 2; ++u) {
        const int e   = tid + u * 256;        // 0..511
        const int row = e >> 3;               // 0..63
        const int kq  = e & 7;                // float4 within row
        const int g   = kq >> 1;              // k-group of 8
        const int hw  = kq & 1;               // which uint2 half
        const int slot = (row >> 4) * 64 + g * 16 + (row & 15);
        {
            const float4 v = ((const float4*)Aq)[e];
            const unsigned h01 = cvt_pk_bf16(v.x, v.y);
            const unsigned h23 = cvt_pk_bf16(v.z, v.w);
            const float r0 = v.x - __uint_as_float(h01 << 16);
            const float r1 = v.y - __uint_as_float(h01 & 0xffff0000u);
            const float r2 = v.z - __uint_as_float(h23 << 16);
            const float r3 = v.w - __uint_as_float(h23 & 0xffff0000u);
            ((uint2*)&Ah[slot])[hw] = make_uint2(h01, h23);
            ((uint2*)&Al[slot])[hw] =
                make_uint2(cvt_pk_bf16(r0, r1), cvt_pk_bf16(r2, r3));
        }
        {
            const float4 v = ((const float4*)Bq)[e];
            const unsigned h01 = cvt_pk_bf16(v.x, v.y);
            const unsigned h23 = cvt_pk_bf16(v.z, v.w);
            const float r0 = v.x - __uint_as_float(h01 << 16);
            const float r1 = v.y - __uint_as_float(h01 & 0xffff0000u);
            const float r2 = v.z - __uint_as_float(h23 << 16);
            const float r3 = v.w - __uint_as_float(h23 & 0xffff0000u);
            ((uint2*)&Bh[slot])[hw] = make_uint2(h01, h23);
            ((uint2*)&Bl[slot])[hw] =
                make_uint2(cvt_pk_bf16(r0, r1), cvt_pk_bf16(r2, r3));
        }
    }
    // Per-row fp32 norms (rows L1-hot from staging).
    if (tid < 128) {
        const int r = tid & 63;
        const float4* rp = (const float4*)((tid < 64 ? Aq : Bq) + (size_t)r * DD);
        float c0 = 0.f, c1 = 0.f, c2 = 0.f, c3 = 0.f;
        #pragma unroll
        for (int k = 0; k < DD / 4; ++k) {
            float4 v = rp[k];
            c0 = fmaf(v.x, v.x, c0);
            c1 = fmaf(v.y, v.y, c1);
            c2 = fmaf(v.z, v.z, c2);
            c3 = fmaf(v.w, v.w, c3);
        }
        (tid < 64 ? a2s : b2s)[r] = (c0 + c1) + (c2 + c3);
    }
    __syncthreads();

    // Compute: wave owns j-tile wv, loops 4 i-tiles.
    const bf16x8 bh = Bh[wv * 64 + lane];
    const bf16x8 bl = Bl[wv * 64 + lane];
    const float  b2 = b2s[wv * 16 + (lane & 15)];
    // exp(negw*nrm) = 2^(negw*log2e*nrm)
    const float  negw2 = -w[b] * (1.0f / (float)DD) * 1.44269504088896f;
    const bool   sym = (type < 2) && (iq == jq);
    const int    rowbase = (lane >> 4) * 4;
    const int    colr = lane & 15;

    float acc = 0.f;
    #pragma unroll
    for (int it = 0; it < 4; ++it) {
        const bf16x8 ah = Ah[it * 64 + lane];
        const bf16x8 al = Al[it * 64 + lane];
        f32x4 c = {0.f, 0.f, 0.f, 0.f};
        c = __builtin_amdgcn_mfma_f32_16x16x32_bf16(al, bh, c, 0, 0, 0);
        c = __builtin_amdgcn_mfma_f32_16x16x32_bf16(ah, bl, c, 0, 0, 0);
        c = __builtin_amdgcn_mfma_f32_16x16x32_bf16(ah, bh, c, 0, 0, 0);
        const f32x4 a2q = *(const f32x4*)&a2s[it * 16 + rowbase];
        const bool diagt = sym && (it == wv);
        #pragma unroll
        for (int r = 0; r < 4; ++r) {
            float sq = fmaf(-2.0f, c[r], a2q[r] + b2);
            if (diagt && (rowbase + r == colr)) sq = 0.f;
            sq = fmaxf(sq, 1e-8f);   // folds norm clamp: sqrt(1e-8) = 1e-4
            acc += fast_exp2(negw2 * fast_sqrt(sq));
        }
    }

    // Deterministic block reduction: wave shuffle + fixed-order cross-wave.
    #pragma unroll
    for (int off = 32; off > 0; off >>= 1) acc += __shfl_down(acc, off, 64);
    __shared__ float red[4];
    if (lane == 0) red[wv] = acc;
    __syncthreads();
    if (tid == 0) {
        const float bsum = (red[0] + red[1]) + (red[2] + red[3]);
        const float scale = weight / ((float)NN * (float)NN * (float)BB);
        partials[blk] = bsum * scale;
    }
}

// Final deterministic reduction of NPART partials in double.
__global__ __launch_bounds__(256) void mmd_reduce(
    const float* __restrict__ partials, float* __restrict__ out) {
    double acc = 0.0;
    #pragma unroll
    for (int t = 0; t < 5; ++t) {
        const int idx = threadIdx.x + t * 256;
        if (idx < NPART) acc += (double)partials[idx];
    }
    #pragma unroll
    for (int off = 32; off > 0; off >>= 1) acc += __shfl_down(acc, off, 64);
    __shared__ double red[4];
    if ((threadIdx.x & 63) == 0) red[threadIdx.x >> 6] = acc;
    __syncthreads();
    if (threadIdx.x == 0)
        out[0] = (float)((red[0] + red[1]) + (red[2] + red[3]));
}

extern "C" void kernel_launch(void* const* d_in, const int* in_sizes, int n_in,
                              void* d_out, int out_size, void* d_ws, size_t ws_size,
                              hipStream_t stream) {
    const float* x = (const float*)d_in[0];
    const float* y = (const float*)d_in[1];
    const float* w = (const float*)d_in[2];
    float* out = (float*)d_out;
    float* partials = (float*)d_ws;  // NPART floats

    mmd_main<<<NBLK, TPB, 0, stream>>>(x, y, w, partials);
    mmd_reduce<<<1, 256, 0, stream>>>(partials, out);
}